// Round 8
// baseline (1806.220 us; speedup 1.0000x reference)
//
#include <hip/hip_runtime.h>

typedef __bf16 bf16x8 __attribute__((ext_vector_type(8)));
typedef float f32x16 __attribute__((ext_vector_type(16)));
typedef float f32x4 __attribute__((ext_vector_type(4)));

#define S_TOTAL 8192
#define DIM 256
#define BK 32

// Block = (batch, kslice, jhalf): 256x128 partial slice via bf16 MFMA.
// 512 thr = 8 waves (4x2 grid of 64x64 tiles, 64 AGPR acc); launch_bounds(512,4)
// caps regs at 128/wave -> 2 blocks/CU = two independent barrier groups (the
// R3/R6 single-group serialization fix). XCD-pair swizzle: jhalf-pair members
// land on the SAME XCD at adjacent slots, so the pair's duplicated A-read hits
// XCD-L2 instead of HBM (fixes R4's +32MB FETCH regression).
// LDS: dbuf subtiled bf16 A[4][256][8] + B[4][128][8] = 24KB/buf, 48KB total;
// ds_write_b128 / ds_read_b128 lane-linear (0 conflicts, proven R4/R6).
__global__ __launch_bounds__(512, 4) void opm_partial(
    const float* __restrict__ A, const float* __restrict__ Bm,
    __bf16* __restrict__ dstbf, float* __restrict__ dstf32,
    int split, int kc, float scale)
{
    __shared__ __bf16 ldsA[2][4 * 256 * 8];   // 2 x 16 KB
    __shared__ __bf16 ldsB[2][4 * 128 * 8];   // 2 x 8 KB

    const int tid = threadIdx.x;
    const int w   = tid >> 6;                 // 0..7
    const int l   = tid & 63;

    // XCD-pair swizzle (assumes XCD = dispatch_index % 8 round-robin):
    // bid = x + 8*(2q + m)  ->  pair p = q*8 + x on XCD x, member m = jhalf.
    const int bid = blockIdx.x;
    const int x = bid & 7;
    const int k = bid >> 3;
    const int jhalf = k & 1;
    const int p = (k >> 1) * 8 + x;           // pair id in [0, 8*split)
    const int batch = p / split;
    const int sp    = p % split;

    const long long base = (long long)batch * S_TOTAL * DIM;
    const int s0 = sp * kc;
    const int wr = w >> 1, wc = w & 1;        // wave position in 4x2 grid
    const int lane31 = l & 31;
    const int hi = l >> 5;
    const int niter = kc / BK;                // even

    // staging roles (R4-proven): kb = w&3 (8 s-rows), chalf = w>>2;
    // lane owns A cols {ca, ca+64}, B col cb (within the 128-col j-slice).
    const int kb  = w & 3;
    const int chalf = w >> 2;
    const int ca = chalf * 128 + l;
    const int cb = chalf * 64 + l;

    f32x16 acc[2][2] = {};
    float rA[24], rB[24];

#define LOAD(r, it) do {                                                        \
    const long long srow = base + (long long)(s0 + (it) * BK + kb * 8) * DIM;   \
    _Pragma("unroll")                                                           \
    for (int e = 0; e < 8; ++e) {                                               \
        r[e]      = A[srow + e * DIM + ca];                                     \
        r[8 + e]  = A[srow + e * DIM + ca + 64];                                \
        r[16 + e] = Bm[srow + e * DIM + jhalf * 128 + cb];                      \
    }                                                                           \
} while (0)

#define CVTWRITE(r, buf) do {                                                   \
    bf16x8 v0, v1, v2;                                                          \
    _Pragma("unroll")                                                           \
    for (int e = 0; e < 8; ++e) {                                               \
        v0[e] = (__bf16)r[e]; v1[e] = (__bf16)r[8 + e]; v2[e] = (__bf16)r[16 + e]; \
    }                                                                           \
    *(bf16x8*)&ldsA[buf][(kb * 256 + ca) * 8]      = v0;                        \
    *(bf16x8*)&ldsA[buf][(kb * 256 + ca + 64) * 8] = v1;                        \
    *(bf16x8*)&ldsB[buf][(kb * 128 + cb) * 8]      = v2;                        \
} while (0)

#define BAR() do {                                                              \
    asm volatile("s_waitcnt lgkmcnt(0)" ::: "memory");                          \
    __builtin_amdgcn_s_barrier();                                               \
} while (0)

    auto compute = [&](int buf) {
        #pragma unroll
        for (int t = 0; t < 2; ++t) {          // 2 k-tiles of 16 within BK=32
            const int kb2 = t * 2 + hi;
            bf16x8 af[2], bfv[2];
            #pragma unroll
            for (int mi = 0; mi < 2; ++mi)
                af[mi] = *(const bf16x8*)&ldsA[buf][(kb2 * 256 + wr * 64 + mi * 32 + lane31) * 8];
            #pragma unroll
            for (int nj = 0; nj < 2; ++nj)
                bfv[nj] = *(const bf16x8*)&ldsB[buf][(kb2 * 128 + wc * 64 + nj * 32 + lane31) * 8];
            #pragma unroll
            for (int mi = 0; mi < 2; ++mi)
                #pragma unroll
                for (int nj = 0; nj < 2; ++nj)
                    acc[mi][nj] = __builtin_amdgcn_mfma_f32_32x32x16_bf16(
                        af[mi], bfv[nj], acc[mi][nj], 0, 0, 0);
        }
    };

    // prologue: tile0 -> buf0; tile1's loads stay in flight across the barrier
    LOAD(rA, 0);
    if (niter > 1) LOAD(rB, 1);
    CVTWRITE(rA, 0);
    BAR();

    for (int bs = 0; bs < niter; bs += 2) {
        if (bs + 2 < niter) LOAD(rA, bs + 2);
        compute(0);
        if (bs + 1 < niter) CVTWRITE(rB, 1);
        BAR();
        if (bs + 1 >= niter) break;
        if (bs + 3 < niter) LOAD(rB, bs + 3);
        compute(1);
        if (bs + 2 < niter) CVTWRITE(rA, 0);
        BAR();
    }

#undef LOAD
#undef CVTWRITE
#undef BAR

    // epilogue: write 256x128 slice
    const long long obase = (long long)(batch * split + sp) * (256 * 256) + jhalf * 128;
    if (dstf32) {
        float* o = dstf32 + obase;
        #pragma unroll
        for (int mi = 0; mi < 2; ++mi)
        #pragma unroll
        for (int nj = 0; nj < 2; ++nj)
        #pragma unroll
        for (int q = 0; q < 16; ++q) {
            const int row = (q & 3) + 8 * (q >> 2) + 4 * hi;
            const int i = wr * 64 + mi * 32 + row;
            const int j = wc * 64 + nj * 32 + lane31;
            o[i * 256 + j] = acc[mi][nj][q] * scale;
        }
    } else {
        __bf16* o = dstbf + obase;
        #pragma unroll
        for (int mi = 0; mi < 2; ++mi)
        #pragma unroll
        for (int nj = 0; nj < 2; ++nj)
        #pragma unroll
        for (int q = 0; q < 16; ++q) {
            const int row = (q & 3) + 8 * (q >> 2) + 4 * hi;
            const int i = wr * 64 + mi * 32 + row;
            const int j = wc * 64 + nj * 32 + lane31;
            o[i * 256 + j] = (__bf16)(acc[mi][nj][q] * scale);
        }
    }
}

// Sum `split` bf16 partials per batch, scale by 1/8192. bf16x8 (16B) per lane.
__global__ __launch_bounds__(256) void opm_reduce(
    const __bf16* __restrict__ ws, float* __restrict__ out, int split)
{
    const int idx = blockIdx.x * 256 + threadIdx.x;   // 65536 groups of 8 f32
    const int b = idx >> 13;                          // 8192 groups per batch
    const int r = idx & 8191;
    const bf16x8* p = (const bf16x8*)ws + (long long)b * split * 8192 + r;
    float s[8] = {0.f, 0.f, 0.f, 0.f, 0.f, 0.f, 0.f, 0.f};
    for (int sp = 0; sp < split; ++sp) {
        bf16x8 v = p[(long long)sp * 8192];
        #pragma unroll
        for (int e = 0; e < 8; ++e) s[e] += (float)v[e];
    }
    f32x4 lo = { s[0], s[1], s[2], s[3] };
    f32x4 hiv = { s[4], s[5], s[6], s[7] };
    lo  *= (1.0f / 8192.0f);
    hiv *= (1.0f / 8192.0f);
    ((f32x4*)out)[idx * 2]     = lo;
    ((f32x4*)out)[idx * 2 + 1] = hiv;
}

extern "C" void kernel_launch(void* const* d_in, const int* in_sizes, int n_in,
                              void* d_out, int out_size, void* d_ws, size_t ws_size,
                              hipStream_t stream)
{
    (void)in_sizes; (void)n_in; (void)out_size;
    const float* A  = (const float*)d_in[0];
    const float* Bm = (const float*)d_in[1];
    float* out = (float*)d_out;

    int split = 32;
    while (split > 1 && (size_t)8 * split * 65536 * sizeof(__bf16) > ws_size) split >>= 1;

    if (split >= 2) {
        const int kc = S_TOTAL / split;
        opm_partial<<<16 * split, 512, 0, stream>>>(A, Bm, (__bf16*)d_ws, nullptr, split, kc, 1.0f);
        opm_reduce<<<256, 256, 0, stream>>>((const __bf16*)d_ws, out, split);
    } else {
        // tiny-ws fallback: 16 blocks over full K, f32 direct to out
        opm_partial<<<16, 512, 0, stream>>>(A, Bm, nullptr, out, 1, S_TOTAL, 1.0f / 8192.0f);
    }
}

// Round 9
// 42.396 us; speedup vs baseline: 42.6034x; 42.6034x over previous
//
#include <hip/hip_runtime.h>

typedef __bf16 bf16x8 __attribute__((ext_vector_type(8)));
typedef float f32x16 __attribute__((ext_vector_type(16)));
typedef float f32x4 __attribute__((ext_vector_type(4)));

#define S_TOTAL 8192
#define DIM 256
#define BK 32

// Block = (batch, k-chunk): full 256x256 partial via bf16 MFMA into bf16 ws.
// Loop interior is byte-identical to R6 (dbuf LDS, 2-deep named-reg prefetch,
// lgkmcnt-only barriers). CHANGE (R9): epilogue repacks the output tile through
// the dead staging LDS (4 bands x 32KB) and stores with lane-consecutive
// bf16x8 (global_store_dwordx4, 1KB/wave-instr) instead of 64 scalar 2-byte
// stores per lane — the write-combine-hostile pattern shared by R2/R3/R6.
__global__ __launch_bounds__(1024) void opm_partial(
    const float* __restrict__ A, const float* __restrict__ Bm,
    __bf16* __restrict__ dstbf, float* __restrict__ dstf32,
    int split, int kc, float scale)
{
    __shared__ __bf16 lds[2][2][4 * 256 * 8];   // 2 buf x 2 mat x 16 KB

    const int tid = threadIdx.x;
    const int w   = tid >> 6;
    const int l   = tid & 63;
    const int batch = blockIdx.x / split;
    const int sp    = blockIdx.x % split;
    const long long base = (long long)batch * S_TOTAL * DIM;
    const int s0 = sp * kc;
    const int wr = w >> 2, wc = w & 3;     // wave position in 4x4 grid
    const int lane31 = l & 31;
    const int hi = l >> 5;
    const int niter = kc / BK;             // 8 (even)

    // staging roles: mat = w>>3 (0:A, 1:B); row-group g = (w&7)>>1 (8 s-rows);
    // col half = w&1; lane owns cols {c0, c0+64}.
    const int mat = w >> 3;
    const int g   = (w & 7) >> 1;
    const int c0  = (w & 1) * 128 + l;
    const float* src = mat ? Bm : A;

    f32x16 acc[2][2] = {};
    float rA[16], rB[16];

#define LOAD(r, it) do {                                                        \
    const long long rowbase = base + (long long)(s0 + (it) * BK + g * 8) * DIM; \
    _Pragma("unroll")                                                           \
    for (int e = 0; e < 8; ++e) {                                               \
        r[e]     = src[rowbase + e * DIM + c0];                                 \
        r[8 + e] = src[rowbase + e * DIM + c0 + 64];                            \
    }                                                                           \
} while (0)

#define CVTWRITE(r, buf) do {                                                   \
    bf16x8 v0, v1;                                                              \
    _Pragma("unroll")                                                           \
    for (int e = 0; e < 8; ++e) { v0[e] = (__bf16)r[e]; v1[e] = (__bf16)r[8 + e]; } \
    *(bf16x8*)&lds[buf][mat][(g * 256 + c0) * 8]      = v0;                     \
    *(bf16x8*)&lds[buf][mat][(g * 256 + c0 + 64) * 8] = v1;                     \
} while (0)

#define BAR() do {                                                              \
    asm volatile("s_waitcnt lgkmcnt(0)" ::: "memory");                          \
    __builtin_amdgcn_s_barrier();                                               \
} while (0)

    auto compute = [&](int buf) {
        #pragma unroll
        for (int t = 0; t < 2; ++t) {          // 2 k-tiles of 16 within BK=32
            const int kb2 = t * 2 + hi;
            bf16x8 af[2], bfv[2];
            #pragma unroll
            for (int mi = 0; mi < 2; ++mi)
                af[mi] = *(const bf16x8*)&lds[buf][0][(kb2 * 256 + wr * 64 + mi * 32 + lane31) * 8];
            #pragma unroll
            for (int nj = 0; nj < 2; ++nj)
                bfv[nj] = *(const bf16x8*)&lds[buf][1][(kb2 * 256 + wc * 64 + nj * 32 + lane31) * 8];
            #pragma unroll
            for (int mi = 0; mi < 2; ++mi)
                #pragma unroll
                for (int nj = 0; nj < 2; ++nj)
                    acc[mi][nj] = __builtin_amdgcn_mfma_f32_32x32x16_bf16(
                        af[mi], bfv[nj], acc[mi][nj], 0, 0, 0);
        }
    };

    // prologue: tile0 -> buf0; tile1 loads in flight
    LOAD(rA, 0);
    LOAD(rB, 1);
    CVTWRITE(rA, 0);        // waits only rA's loads (rB stays outstanding)
    BAR();

    for (int bs = 0; bs < niter; bs += 2) {
        if (bs + 2 < niter) LOAD(rA, bs + 2);
        compute(0);
        CVTWRITE(rB, 1);
        BAR();
        if (bs + 3 < niter) LOAD(rB, bs + 3);
        compute(1);
        if (bs + 2 < niter) { CVTWRITE(rA, 0); }
        BAR();
    }

#undef LOAD
#undef CVTWRITE
#undef BAR

    // ---- epilogue ----
    const long long obase = (long long)blockIdx.x * (256 * 256);
    if (dstf32) {
        // fallback path (tiny ws): correctness-only scalar stores
        float* o = dstf32 + obase;
        #pragma unroll
        for (int mi = 0; mi < 2; ++mi)
        #pragma unroll
        for (int nj = 0; nj < 2; ++nj)
        #pragma unroll
        for (int q = 0; q < 16; ++q) {
            const int row = (q & 3) + 8 * (q >> 2) + 4 * hi;
            const int i = wr * 64 + mi * 32 + row;
            const int j = wc * 64 + nj * 32 + lane31;
            o[i * 256 + j] = acc[mi][nj][q] * scale;
        }
    } else {
        // bf16 ws path: LDS band-repack -> wide coalesced stores.
        __bf16* o = dstbf + obase;
        __bf16* ebuf = &lds[0][0][0];        // 32 KB band buffer (staging LDS is dead)
        #pragma unroll
        for (int band = 0; band < 4; ++band) {
            __syncthreads();                 // previous band fully read
            if (wr == band) {
                #pragma unroll
                for (int mi = 0; mi < 2; ++mi)
                #pragma unroll
                for (int nj = 0; nj < 2; ++nj)
                #pragma unroll
                for (int q = 0; q < 16; ++q) {
                    const int row = mi * 32 + (q & 3) + 8 * (q >> 2) + 4 * hi;
                    const int col = wc * 64 + nj * 32 + lane31;
                    ebuf[row * 256 + col] = (__bf16)(acc[mi][nj][q] * scale);
                }
            }
            __syncthreads();
            // cooperative store: 32 KB band, 1024 threads x 32 B, lane-consecutive 16 B
            bf16x8 v0 = *(const bf16x8*)&ebuf[tid * 8];
            bf16x8 v1 = *(const bf16x8*)&ebuf[8192 + tid * 8];
            *(bf16x8*)&o[band * 16384 + tid * 8] = v0;
            *(bf16x8*)&o[band * 16384 + 8192 + tid * 8] = v1;
        }
    }
}

// Sum `split` bf16 partials per batch, scale by 1/8192. bf16x8 (16B) per lane.
__global__ __launch_bounds__(256) void opm_reduce(
    const __bf16* __restrict__ ws, float* __restrict__ out, int split)
{
    const int idx = blockIdx.x * 256 + threadIdx.x;   // 65536 groups of 8 f32
    const int b = idx >> 13;                          // 8192 groups per batch
    const int r = idx & 8191;
    const bf16x8* p = (const bf16x8*)ws + (long long)b * split * 8192 + r;
    float s[8] = {0.f, 0.f, 0.f, 0.f, 0.f, 0.f, 0.f, 0.f};
    for (int sp = 0; sp < split; ++sp) {
        bf16x8 v = p[(long long)sp * 8192];
        #pragma unroll
        for (int e = 0; e < 8; ++e) s[e] += (float)v[e];
    }
    f32x4 lo = { s[0], s[1], s[2], s[3] };
    f32x4 hiv = { s[4], s[5], s[6], s[7] };
    lo  *= (1.0f / 8192.0f);
    hiv *= (1.0f / 8192.0f);
    ((f32x4*)out)[idx * 2]     = lo;
    ((f32x4*)out)[idx * 2 + 1] = hiv;
}

extern "C" void kernel_launch(void* const* d_in, const int* in_sizes, int n_in,
                              void* d_out, int out_size, void* d_ws, size_t ws_size,
                              hipStream_t stream)
{
    (void)in_sizes; (void)n_in; (void)out_size;
    const float* A  = (const float*)d_in[0];
    const float* Bm = (const float*)d_in[1];
    float* out = (float*)d_out;

    int split = 32;
    while (split > 1 && (size_t)8 * split * 65536 * sizeof(__bf16) > ws_size) split >>= 1;

    if (split >= 2) {
        const int kc = S_TOTAL / split;
        opm_partial<<<8 * split, 1024, 0, stream>>>(A, Bm, (__bf16*)d_ws, nullptr, split, kc, 1.0f);
        opm_reduce<<<256, 256, 0, stream>>>((const __bf16*)d_ws, out, split);
    } else {
        // tiny-ws fallback: one block per batch over full K, f32 direct to out
        opm_partial<<<8, 1024, 0, stream>>>(A, Bm, nullptr, out, 1, S_TOTAL, 1.0f / 8192.0f);
    }
}

// Round 10
// 39.953 us; speedup vs baseline: 45.2085x; 1.0611x over previous
//
#include <hip/hip_runtime.h>

typedef __bf16 bf16x8 __attribute__((ext_vector_type(8)));
typedef float f32x16 __attribute__((ext_vector_type(16)));
typedef float f32x4 __attribute__((ext_vector_type(4)));

#define S_TOTAL 8192
#define DIM 256
#define BK 32
#define SPLIT 32

// Block = (batch, k-chunk): full 256x256 partial via bf16 MFMA into bf16 ws.
// Interior proven/neutral-stable across R2/R3/R6/R9 (~its memory floor):
// dbuf LDS, 2-deep named-reg prefetch, lgkmcnt-only barriers, LDS band-repack
// epilogue with bf16x8 coalesced stores (WRITE_SIZE exactly 32MB, R9-verified).
__global__ __launch_bounds__(1024) void opm_partial(
    const float* __restrict__ A, const float* __restrict__ Bm,
    __bf16* __restrict__ dstbf, float* __restrict__ dstf32,
    int split, int kc, float scale)
{
    __shared__ __bf16 lds[2][2][4 * 256 * 8];   // 2 buf x 2 mat x 16 KB

    const int tid = threadIdx.x;
    const int w   = tid >> 6;
    const int l   = tid & 63;
    const int batch = blockIdx.x / split;
    const int sp    = blockIdx.x % split;
    const long long base = (long long)batch * S_TOTAL * DIM;
    const int s0 = sp * kc;
    const int wr = w >> 2, wc = w & 3;     // wave position in 4x4 grid
    const int lane31 = l & 31;
    const int hi = l >> 5;
    const int niter = kc / BK;             // 8 (even)

    const int mat = w >> 3;
    const int g   = (w & 7) >> 1;
    const int c0  = (w & 1) * 128 + l;
    const float* src = mat ? Bm : A;

    f32x16 acc[2][2] = {};
    float rA[16], rB[16];

#define LOAD(r, it) do {                                                        \
    const long long rowbase = base + (long long)(s0 + (it) * BK + g * 8) * DIM; \
    _Pragma("unroll")                                                           \
    for (int e = 0; e < 8; ++e) {                                               \
        r[e]     = src[rowbase + e * DIM + c0];                                 \
        r[8 + e] = src[rowbase + e * DIM + c0 + 64];                            \
    }                                                                           \
} while (0)

#define CVTWRITE(r, buf) do {                                                   \
    bf16x8 v0, v1;                                                              \
    _Pragma("unroll")                                                           \
    for (int e = 0; e < 8; ++e) { v0[e] = (__bf16)r[e]; v1[e] = (__bf16)r[8 + e]; } \
    *(bf16x8*)&lds[buf][mat][(g * 256 + c0) * 8]      = v0;                     \
    *(bf16x8*)&lds[buf][mat][(g * 256 + c0 + 64) * 8] = v1;                     \
} while (0)

#define BAR() do {                                                              \
    asm volatile("s_waitcnt lgkmcnt(0)" ::: "memory");                          \
    __builtin_amdgcn_s_barrier();                                               \
} while (0)

    auto compute = [&](int buf) {
        #pragma unroll
        for (int t = 0; t < 2; ++t) {
            const int kb2 = t * 2 + hi;
            bf16x8 af[2], bfv[2];
            #pragma unroll
            for (int mi = 0; mi < 2; ++mi)
                af[mi] = *(const bf16x8*)&lds[buf][0][(kb2 * 256 + wr * 64 + mi * 32 + lane31) * 8];
            #pragma unroll
            for (int nj = 0; nj < 2; ++nj)
                bfv[nj] = *(const bf16x8*)&lds[buf][1][(kb2 * 256 + wc * 64 + nj * 32 + lane31) * 8];
            #pragma unroll
            for (int mi = 0; mi < 2; ++mi)
                #pragma unroll
                for (int nj = 0; nj < 2; ++nj)
                    acc[mi][nj] = __builtin_amdgcn_mfma_f32_32x32x16_bf16(
                        af[mi], bfv[nj], acc[mi][nj], 0, 0, 0);
        }
    };

    LOAD(rA, 0);
    LOAD(rB, 1);
    CVTWRITE(rA, 0);
    BAR();

    for (int bs = 0; bs < niter; bs += 2) {
        if (bs + 2 < niter) LOAD(rA, bs + 2);
        compute(0);
        CVTWRITE(rB, 1);
        BAR();
        if (bs + 3 < niter) LOAD(rB, bs + 3);
        compute(1);
        if (bs + 2 < niter) { CVTWRITE(rA, 0); }
        BAR();
    }

#undef LOAD
#undef CVTWRITE
#undef BAR

    const long long obase = (long long)blockIdx.x * (256 * 256);
    if (dstf32) {
        float* o = dstf32 + obase;
        #pragma unroll
        for (int mi = 0; mi < 2; ++mi)
        #pragma unroll
        for (int nj = 0; nj < 2; ++nj)
        #pragma unroll
        for (int q = 0; q < 16; ++q) {
            const int row = (q & 3) + 8 * (q >> 2) + 4 * hi;
            const int i = wr * 64 + mi * 32 + row;
            const int j = wc * 64 + nj * 32 + lane31;
            o[i * 256 + j] = acc[mi][nj][q] * scale;
        }
    } else {
        __bf16* o = dstbf + obase;
        __bf16* ebuf = &lds[0][0][0];
        #pragma unroll
        for (int band = 0; band < 4; ++band) {
            __syncthreads();
            if (wr == band) {
                #pragma unroll
                for (int mi = 0; mi < 2; ++mi)
                #pragma unroll
                for (int nj = 0; nj < 2; ++nj)
                #pragma unroll
                for (int q = 0; q < 16; ++q) {
                    const int row = mi * 32 + (q & 3) + 8 * (q >> 2) + 4 * hi;
                    const int col = wc * 64 + nj * 32 + lane31;
                    ebuf[row * 256 + col] = (__bf16)(acc[mi][nj][q] * scale);
                }
            }
            __syncthreads();
            bf16x8 v0 = *(const bf16x8*)&ebuf[tid * 8];
            bf16x8 v1 = *(const bf16x8*)&ebuf[8192 + tid * 8];
            *(bf16x8*)&o[band * 16384 + tid * 8] = v0;
            *(bf16x8*)&o[band * 16384 + 8192 + tid * 8] = v1;
        }
    }
}

// R10: SPLIT hardcoded + fully-unrolled sp-loop -> 32 independent bf16x8 loads
// per thread (MLP=32, ~128KB in flight per CU) so the reduce is BW-bound, not
// HBM-latency-bound (the old runtime-trip loop couldn't unroll; 4 waves/CU at
// MLP~2 was latency-bound ~15us).
__global__ __launch_bounds__(256) void opm_reduce32(
    const __bf16* __restrict__ ws, float* __restrict__ out)
{
    const int idx = blockIdx.x * 256 + threadIdx.x;   // 65536 groups of 8 f32
    const int b = idx >> 13;                          // 8192 groups per batch
    const int r = idx & 8191;
    const bf16x8* p = (const bf16x8*)ws + ((long long)b * SPLIT) * 8192 + r;

    bf16x8 v[SPLIT];
    #pragma unroll
    for (int sp = 0; sp < SPLIT; ++sp) v[sp] = p[sp * 8192];   // all independent

    float s[8] = {0.f, 0.f, 0.f, 0.f, 0.f, 0.f, 0.f, 0.f};
    #pragma unroll
    for (int sp = 0; sp < SPLIT; ++sp)
        #pragma unroll
        for (int e = 0; e < 8; ++e) s[e] += (float)v[sp][e];

    f32x4 lo = { s[0], s[1], s[2], s[3] };
    f32x4 hiv = { s[4], s[5], s[6], s[7] };
    lo  *= (1.0f / 8192.0f);
    hiv *= (1.0f / 8192.0f);
    ((f32x4*)out)[idx * 2]     = lo;
    ((f32x4*)out)[idx * 2 + 1] = hiv;
}

// generic fallback (split != 32)
__global__ __launch_bounds__(256) void opm_reduce(
    const __bf16* __restrict__ ws, float* __restrict__ out, int split)
{
    const int idx = blockIdx.x * 256 + threadIdx.x;
    const int b = idx >> 13;
    const int r = idx & 8191;
    const bf16x8* p = (const bf16x8*)ws + (long long)b * split * 8192 + r;
    float s[8] = {0.f, 0.f, 0.f, 0.f, 0.f, 0.f, 0.f, 0.f};
    for (int sp = 0; sp < split; ++sp) {
        bf16x8 v = p[(long long)sp * 8192];
        #pragma unroll
        for (int e = 0; e < 8; ++e) s[e] += (float)v[e];
    }
    f32x4 lo = { s[0], s[1], s[2], s[3] };
    f32x4 hiv = { s[4], s[5], s[6], s[7] };
    lo  *= (1.0f / 8192.0f);
    hiv *= (1.0f / 8192.0f);
    ((f32x4*)out)[idx * 2]     = lo;
    ((f32x4*)out)[idx * 2 + 1] = hiv;
}

extern "C" void kernel_launch(void* const* d_in, const int* in_sizes, int n_in,
                              void* d_out, int out_size, void* d_ws, size_t ws_size,
                              hipStream_t stream)
{
    (void)in_sizes; (void)n_in; (void)out_size;
    const float* A  = (const float*)d_in[0];
    const float* Bm = (const float*)d_in[1];
    float* out = (float*)d_out;

    int split = 32;
    while (split > 1 && (size_t)8 * split * 65536 * sizeof(__bf16) > ws_size) split >>= 1;

    if (split == 32) {
        opm_partial<<<8 * 32, 1024, 0, stream>>>(A, Bm, (__bf16*)d_ws, nullptr, 32, S_TOTAL / 32, 1.0f);
        opm_reduce32<<<256, 256, 0, stream>>>((const __bf16*)d_ws, out);
    } else if (split >= 2) {
        const int kc = S_TOTAL / split;
        opm_partial<<<8 * split, 1024, 0, stream>>>(A, Bm, (__bf16*)d_ws, nullptr, split, kc, 1.0f);
        opm_reduce<<<256, 256, 0, stream>>>((const __bf16*)d_ws, out, split);
    } else {
        opm_partial<<<8, 1024, 0, stream>>>(A, Bm, nullptr, out, 1, S_TOTAL, 1.0f / 8192.0f);
    }
}

// Round 11
// 39.022 us; speedup vs baseline: 46.2871x; 1.0239x over previous
//
#include <hip/hip_runtime.h>

typedef __bf16 bf16x8 __attribute__((ext_vector_type(8)));
typedef float f32x16 __attribute__((ext_vector_type(16)));
typedef float f32x4 __attribute__((ext_vector_type(4)));

#define S_TOTAL 8192
#define DIM 256
#define BK 16
#define SPLIT 32

// R11: 2 blocks/CU partial. Block = (batch, sp, jhalf) computes a 256x128
// partial slice. 512 thr = 8 waves (4x2 of 64x64, 64 AGPR acc). Staging is
// pure global_load_lds DMA (ZERO staging VGPRs -> no R8 spill) into
// triple-buffered f32 LDS (A 16KB + B 8KB per buf, 72KB/block, 144KB/CU).
// Pipeline: counted vmcnt(3), ONE barrier/iter, issue T_{i+2} after the
// barrier (3-buf makes this race-free: barrier #i orders all compute T_{i-1}
// before T_{i+2}'s DMA hits the same buffer). XCD-pair swizzle puts the two
// jhalf-members of each (batch,sp) on the SAME XCD so their duplicated
// A-panel read hits that XCD's L2 (fixes R4's +32MB FETCH).
__global__ __launch_bounds__(512, 4) void opm_partial(
    const float* __restrict__ A, const float* __restrict__ Bm,
    __bf16* __restrict__ dstbf, float* __restrict__ dstf32,
    int split, int kc, float scale)
{
    __shared__ float lA[3][BK * 256];   // 3 x 16 KB
    __shared__ float lB[3][BK * 128];   // 3 x 8 KB

    const int tid = threadIdx.x;
    const int w   = tid >> 6;            // 0..7
    const int l   = tid & 63;

    // XCD-pair swizzle: bid = x + 8*(2q + m) -> pair p = q*8+x on XCD x.
    const int bid = blockIdx.x;
    const int x  = bid & 7;
    const int k  = bid >> 3;
    const int jh = k & 1;
    const int p  = (k >> 1) * 8 + x;
    const int batch = p / split;
    const int sp    = p % split;

    const long long base = (long long)batch * S_TOTAL * DIM;
    const int s0 = sp * kc;
    const int wr = w >> 1, wc = w & 1;   // wave position in 4x2 grid
    const int lane31 = l & 31;
    const int hi = l >> 5;
    const int niter = kc / BK;

    f32x16 acc[2][2] = {};

    // DMA slots per wave: A rows {w, w+8}, B row-pair {2w, 2w+1}. 3 instrs/wave.
    auto issue = [&](int it) {
        const int b3 = it % 3;
        const long long sb = (long long)(s0 + it * BK);
        // A row w (1 KB): per-lane global, wave-uniform LDS row base (+lane*16 HW)
        __builtin_amdgcn_global_load_lds(
            (const __attribute__((address_space(1))) unsigned int*)(A + base + (sb + w) * DIM + 4 * l),
            (__attribute__((address_space(3))) unsigned int*)&lA[b3][w * 256], 16, 0, 0);
        // A row w+8
        __builtin_amdgcn_global_load_lds(
            (const __attribute__((address_space(1))) unsigned int*)(A + base + (sb + w + 8) * DIM + 4 * l),
            (__attribute__((address_space(3))) unsigned int*)&lA[b3][(w + 8) * 256], 16, 0, 0);
        // B rows 2w, 2w+1 (512 B each; lanes 0-31 -> row 2w, 32-63 -> row 2w+1)
        __builtin_amdgcn_global_load_lds(
            (const __attribute__((address_space(1))) unsigned int*)(Bm + base + (sb + 2 * w + (l >> 5)) * DIM + jh * 128 + 4 * (l & 31)),
            (__attribute__((address_space(3))) unsigned int*)&lB[b3][2 * w * 128], 16, 0, 0);
    };

    auto compute = [&](int b3) {
        const int i0 = wr * 64 + lane31;
        const int j0 = wc * 64 + lane31;
        bf16x8 af[2], bfv[2];
        #pragma unroll
        for (int mi = 0; mi < 2; ++mi)
            #pragma unroll
            for (int e = 0; e < 8; ++e)
                af[mi][e] = (__bf16)lA[b3][(hi * 8 + e) * 256 + i0 + mi * 32];
        #pragma unroll
        for (int nj = 0; nj < 2; ++nj)
            #pragma unroll
            for (int e = 0; e < 8; ++e)
                bfv[nj][e] = (__bf16)lB[b3][(hi * 8 + e) * 128 + j0 + nj * 32];
        #pragma unroll
        for (int mi = 0; mi < 2; ++mi)
            #pragma unroll
            for (int nj = 0; nj < 2; ++nj)
                acc[mi][nj] = __builtin_amdgcn_mfma_f32_32x32x16_bf16(
                    af[mi], bfv[nj], acc[mi][nj], 0, 0, 0);
    };

    // prologue: T0, T1 in flight
    issue(0);
    issue(1);

    for (int it = 0; it < niter; ++it) {
        if (it + 1 < niter) asm volatile("s_waitcnt vmcnt(3)" ::: "memory");  // T_it done, T_{it+1} outstanding
        else                asm volatile("s_waitcnt vmcnt(0)" ::: "memory");
        __builtin_amdgcn_s_barrier();            // all waves' slots for T_it landed
        if (it + 2 < niter) issue(it + 2);       // post-barrier: safe to overwrite buf (it+2)%3
        compute(it % 3);
    }

    // ---- epilogue: 256x128 slice ----
    if (dstf32) {
        float* o = dstf32 + (long long)batch * (256 * 256) + jh * 128;
        #pragma unroll
        for (int mi = 0; mi < 2; ++mi)
        #pragma unroll
        for (int nj = 0; nj < 2; ++nj)
        #pragma unroll
        for (int q = 0; q < 16; ++q) {
            const int row = (q & 3) + 8 * (q >> 2) + 4 * hi;
            const int i = wr * 64 + mi * 32 + row;
            const int j = wc * 64 + nj * 32 + lane31;
            o[i * 256 + j] = acc[mi][nj][q] * scale;
        }
    } else {
        // band-repack through (now dead) lA, then coalesced bf16x8 stores
        __bf16* o = dstbf + (long long)(batch * split + sp) * (256 * 256) + jh * 128;
        __bf16* ebuf = (__bf16*)&lA[0][0];       // 16 KB band: 64 rows x 128 cols
        #pragma unroll
        for (int band = 0; band < 4; ++band) {
            __syncthreads();
            if (wr == band) {
                #pragma unroll
                for (int mi = 0; mi < 2; ++mi)
                #pragma unroll
                for (int nj = 0; nj < 2; ++nj)
                #pragma unroll
                for (int q = 0; q < 16; ++q) {
                    const int row = mi * 32 + (q & 3) + 8 * (q >> 2) + 4 * hi;
                    const int col = wc * 64 + nj * 32 + lane31;
                    ebuf[row * 128 + col] = (__bf16)(acc[mi][nj][q] * scale);
                }
            }
            __syncthreads();
            // 1024 groups of bf16x8; 512 threads x 2
            #pragma unroll
            for (int h = 0; h < 2; ++h) {
                const int G = tid + h * 512;
                const int r = G >> 4, c8 = (G & 15) * 8;
                bf16x8 v = *(const bf16x8*)&ebuf[r * 128 + c8];
                *(bf16x8*)&o[(band * 64 + r) * 256 + c8] = v;
            }
        }
    }
}

// R10-proven reduce: SPLIT unrolled -> 32 independent bf16x8 loads (BW-bound).
__global__ __launch_bounds__(256) void opm_reduce32(
    const __bf16* __restrict__ ws, float* __restrict__ out)
{
    const int idx = blockIdx.x * 256 + threadIdx.x;
    const int b = idx >> 13;
    const int r = idx & 8191;
    const bf16x8* p = (const bf16x8*)ws + ((long long)b * SPLIT) * 8192 + r;

    bf16x8 v[SPLIT];
    #pragma unroll
    for (int sp = 0; sp < SPLIT; ++sp) v[sp] = p[sp * 8192];

    float s[8] = {0.f, 0.f, 0.f, 0.f, 0.f, 0.f, 0.f, 0.f};
    #pragma unroll
    for (int sp = 0; sp < SPLIT; ++sp)
        #pragma unroll
        for (int e = 0; e < 8; ++e) s[e] += (float)v[sp][e];

    f32x4 lo = { s[0], s[1], s[2], s[3] };
    f32x4 hiv = { s[4], s[5], s[6], s[7] };
    lo  *= (1.0f / 8192.0f);
    hiv *= (1.0f / 8192.0f);
    ((f32x4*)out)[idx * 2]     = lo;
    ((f32x4*)out)[idx * 2 + 1] = hiv;
}

extern "C" void kernel_launch(void* const* d_in, const int* in_sizes, int n_in,
                              void* d_out, int out_size, void* d_ws, size_t ws_size,
                              hipStream_t stream)
{
    (void)in_sizes; (void)n_in; (void)out_size;
    const float* A  = (const float*)d_in[0];
    const float* Bm = (const float*)d_in[1];
    float* out = (float*)d_out;

    if (ws_size >= (size_t)8 * SPLIT * 65536 * sizeof(__bf16)) {
        opm_partial<<<16 * SPLIT, 512, 0, stream>>>(A, Bm, (__bf16*)d_ws, nullptr,
                                                    SPLIT, S_TOTAL / SPLIT, 1.0f);
        opm_reduce32<<<256, 256, 0, stream>>>((const __bf16*)d_ws, out);
    } else {
        // tiny-ws fallback: 16 blocks (8 batches x 2 jhalves) over full K, f32 direct
        opm_partial<<<16, 512, 0, stream>>>(A, Bm, nullptr, out, 1, S_TOTAL, 1.0f / 8192.0f);
    }
}